// Round 15
// baseline (70.460 us; speedup 1.0000x reference)
//
#include <hip/hip_runtime.h>
#include <math.h>

// Problem constants
#define BATCH 64
#define HH 512
#define WW 512
#define PAD 15
#define NELEM ((size_t)BATCH * HH * WW)
#define INV_KK (1.0f / 961.0f)

#define RPW 8                  // rows per wave (independent)
#define TILE_H 32              // 4 waves x 8 rows per block
#define BPI (HH / TILE_H)      // 16 block-tiles per image
#define NBLK (BATCH * BPI)     // 1024 blocks
#define NXCD 8

typedef float f4 __attribute__((ext_vector_type(4)));

__device__ __forceinline__ float wave_reduce(float v) {
    #pragma unroll
    for (int off = 32; off; off >>= 1) v += __shfl_down(v, off, 64);
    return v;
}

// ---------------------------------------------------------------------------
// Barrier-free waves, champion per-wave pipeline. Each wave independently
// owns 8 rows of one image (no producer/consumer split, no main-loop
// __syncthreads -> a stalled wave no longer blocks the CU's other waves):
//  - lane keeps rolling vertical 31-sums for cols 8L..8L+7 in 8 regs
//    (f4 init/slide loads, R7-proven)
//  - per row: local 8-elem prefix + 6-step wave shuffle scan -> write
//    inclusive prefix to wave-private LDS row P[wv] (no vrow buffer at all)
//  - loss at w = lane+64k: stride-1 P reads (conflict-free) + coalesced
//    scalar mask/pred loads — bit-identical math to the champion
//  - same-wave DS ordering makes P[wv] writes/reads safe without barriers
//    (validated R9/R10); the only barrier is the final block reduction.
// Init reads 31 halo rows per 8 output rows (vs 31/32 in R11) — extra mask
// re-reads are L2/L3 hits, traded for full latency decoupling.
// ---------------------------------------------------------------------------
__global__ __launch_bounds__(256) void fused_kernel(const float* __restrict__ pred,
                                                    const float* __restrict__ mask,
                                                    double* __restrict__ partials) {
    __shared__ float P[4][WW];     // one prefix row per wave
    __shared__ float red[3][4];

    // XCD swizzle: xcd = f%8 (HW round-robin); each XCD owns 8 whole images.
    const int f    = blockIdx.x;
    const int xcd  = f & (NXCD - 1);
    const int slot = f >> 3;               // 0..127
    const int img  = xcd * 8 + (slot >> 4);
    const int t    = slot & (BPI - 1);     // block-tile within image

    const int tid  = threadIdx.x;
    const int lane = tid & 63;
    const int wv   = tid >> 6;
    const int h0   = t * TILE_H + wv * RPW;   // wave's first row (max 504!)
    const int c    = 8 * lane;                // lane's producer columns

    const float* mb = mask + (size_t)img * HH * WW;
    const float* pb = pred + (size_t)img * HH * WW;

    // --- init rolling vertical window for row h0 ---
    // CLAMP hi: h0 max 504 -> h0+15 = 519 would be OOB (R5/R6 crash lesson).
    float r0 = 0.f, r1 = 0.f, r2 = 0.f, r3 = 0.f, r4 = 0.f, r5 = 0.f, r6 = 0.f, r7 = 0.f;
    {
        int lo = h0 - PAD; if (lo < 0) lo = 0;
        int hi = h0 + PAD; if (hi > HH - 1) hi = HH - 1;
        for (int y = lo; y <= hi; ++y) {
            f4 m0 = *(const f4*)&mb[(size_t)y * WW + c];
            f4 m1 = *(const f4*)&mb[(size_t)y * WW + c + 4];
            r0 += m0.x; r1 += m0.y; r2 += m0.z; r3 += m0.w;
            r4 += m1.x; r5 += m1.y; r6 += m1.z; r7 += m1.w;
        }
    }

    float accb = 0.0f, acci = 0.0f, accu = 0.0f;
    float* Prow = P[wv];

    #pragma unroll 1   // keep body compact; protects the register budget
    for (int j = 0; j < RPW; ++j) {
        const int h = h0 + j;
        const size_t rbase = (size_t)h * WW;

        // --- local inclusive prefix of the 8 vertical sums ---
        const float p0 = r0;
        const float p1 = p0 + r1;
        const float p2 = p1 + r2;
        const float p3 = p2 + r3;
        const float p4 = p3 + r4;
        const float p5 = p4 + r5;
        const float p6 = p5 + r6;
        const float p7 = p6 + r7;

        // --- wave inclusive scan of lane totals ---
        float incl = p7;
        #pragma unroll
        for (int off = 1; off < 64; off <<= 1) {
            float n = __shfl_up(incl, off, 64);
            if (lane >= off) incl += n;
        }
        const float excl = incl - p7;

        // --- publish prefix row (wave-private, no barrier) ---
        f4 Pa, Pb;
        Pa.x = excl + p0; Pa.y = excl + p1; Pa.z = excl + p2; Pa.w = excl + p3;
        Pb.x = excl + p4; Pb.y = excl + p5; Pb.z = excl + p6; Pb.w = excl + p7;
        *(f4*)&Prow[c]     = Pa;
        *(f4*)&Prow[c + 4] = Pb;

        // --- loss: lane owns w = lane + 64k (stride-1 P reads) ---
        #pragma unroll
        for (int k = 0; k < 8; ++k) {
            const int w = lane + 64 * k;
            int hiw = w + PAD; if (hiw > WW - 1) hiw = WW - 1;
            float s = Prow[hiw];
            if (w >= PAD + 1) s -= Prow[w - PAD - 1];

            const float m  = mb[rbase + w];
            const float pr = pb[rbase + w];

            const float weit = 1.0f + 5.0f * fabsf(s * INV_KK - m);
            const float e    = __expf(-fabsf(pr));
            const float bce  = fmaxf(pr, 0.0f) - pr * m + __logf(1.0f + e);
            const float inv  = __builtin_amdgcn_rcpf(1.0f + e);
            const float p    = (pr >= 0.0f) ? inv : e * inv;   // sigmoid(pr)

            accb += bce;
            acci += p * m * weit;
            accu += (p + m) * weit;
        }

        // --- slide the vertical window (wave-uniform branches) ---
        const int add = h + PAD + 1;
        const int sub = h - PAD;
        if (add < HH) {
            f4 a0 = *(const f4*)&mb[(size_t)add * WW + c];
            f4 a1 = *(const f4*)&mb[(size_t)add * WW + c + 4];
            r0 += a0.x; r1 += a0.y; r2 += a0.z; r3 += a0.w;
            r4 += a1.x; r5 += a1.y; r6 += a1.z; r7 += a1.w;
        }
        if (sub >= 0) {
            f4 s0 = *(const f4*)&mb[(size_t)sub * WW + c];
            f4 s1 = *(const f4*)&mb[(size_t)sub * WW + c + 4];
            r0 -= s0.x; r1 -= s0.y; r2 -= s0.z; r3 -= s0.w;
            r4 -= s1.x; r5 -= s1.y; r6 -= s1.z; r7 -= s1.w;
        }
    }

    // --- block reduction (the only barrier) ---
    accb = wave_reduce(accb);
    acci = wave_reduce(acci);
    accu = wave_reduce(accu);
    if (lane == 0) { red[0][wv] = accb; red[1][wv] = acci; red[2][wv] = accu; }
    __syncthreads();
    if (tid == 0) {
        double bt = (double)red[0][0] + red[0][1] + red[0][2] + red[0][3];
        double it2 = (double)red[1][0] + red[1][1] + red[1][2] + red[1][3];
        double ut = (double)red[2][0] + red[2][1] + red[2][2] + red[2][3];
        const size_t pidx = (size_t)img * BPI + t;   // un-swizzled index
        partials[pidx * 3 + 0] = bt;
        partials[pidx * 3 + 1] = it2;
        partials[pidx * 3 + 2] = ut;
    }
}

// ---------------------------------------------------------------------------
// Finalize from per-block partials (indexed img*BPI + tile), NBLK = 1024.
// ---------------------------------------------------------------------------
__global__ __launch_bounds__(256) void finalize_kernel(const double* __restrict__ partials,
                                                       float* __restrict__ out) {
    __shared__ double redbce[4];
    int tid = threadIdx.x, lane = tid & 63, wv = tid >> 6;

    double bsum = 0.0;
    for (int i = tid; i < NBLK; i += 256) bsum += partials[(size_t)i * 3 + 0];
    #pragma unroll
    for (int off = 32; off; off >>= 1) bsum += __shfl_down(bsum, off, 64);
    if (lane == 0) redbce[wv] = bsum;
    __syncthreads();

    double wiou_term = 0.0;
    if (tid < 64) {
        int bb = tid;
        double it = 0.0, ut = 0.0;
        for (int j = 0; j < BPI; ++j) {
            it += partials[(size_t)(bb * BPI + j) * 3 + 1];
            ut += partials[(size_t)(bb * BPI + j) * 3 + 2];
        }
        wiou_term = 1.0 - (it + 1.0) / (ut - it + 1.0);
    }
    if (wv == 0) {
        #pragma unroll
        for (int off = 32; off; off >>= 1) wiou_term += __shfl_down(wiou_term, off, 64);
    }
    if (tid == 0) {
        double wbce = (redbce[0] + redbce[1] + redbce[2] + redbce[3]) / (double)NELEM;
        out[0] = (float)(wbce + wiou_term * (1.0 / 64.0));
    }
}

// ---------------------------------------------------------------------------
// Fallback path (tiny ws): recompute vertical sums in-kernel + atomics.
// ---------------------------------------------------------------------------
#define ACC_DOUBLES 129
__global__ __launch_bounds__(256) void rowpass_nows_kernel(const float* __restrict__ pred,
                                                           const float* __restrict__ mask,
                                                           double* __restrict__ acc) {
    __shared__ float vrow1[WW];
    __shared__ float red[3][4];
    int b = blockIdx.x / HH;
    int h = blockIdx.x % HH;
    int lo = h - PAD; if (lo < 0) lo = 0;
    int hi = h + PAD; if (hi > HH - 1) hi = HH - 1;
    float s0 = 0.0f, s1 = 0.0f;
    const float* mb = mask + (size_t)b * HH * WW;
    for (int y = lo; y <= hi; ++y) {
        s0 += mb[(size_t)y * WW + threadIdx.x];
        s1 += mb[(size_t)y * WW + threadIdx.x + 256];
    }
    vrow1[threadIdx.x]       = s0;
    vrow1[threadIdx.x + 256] = s1;
    __syncthreads();

    size_t base = ((size_t)b * HH + h) * WW;
    float bce_p = 0.0f, inter_p = 0.0f, uni_p = 0.0f;
    for (int w = threadIdx.x; w < WW; w += 256) {
        int wlo = w - PAD; if (wlo < 0) wlo = 0;
        int whi = w + PAD; if (whi > WW - 1) whi = WW - 1;
        float s = 0.0f;
        for (int k = wlo; k <= whi; ++k) s += vrow1[k];
        float m  = mask[base + w];
        float pr = pred[base + w];
        float weit = 1.0f + 5.0f * fabsf(s * INV_KK - m);
        float e   = expf(-fabsf(pr));
        float bce = fmaxf(pr, 0.0f) - pr * m + log1pf(e);
        float inv = 1.0f / (1.0f + e);
        float p   = (pr >= 0.0f) ? inv : e * inv;
        bce_p += bce; inter_p += p * m * weit; uni_p += (p + m) * weit;
    }
    int lane = threadIdx.x & 63, wvv = threadIdx.x >> 6;
    bce_p = wave_reduce(bce_p); inter_p = wave_reduce(inter_p); uni_p = wave_reduce(uni_p);
    if (lane == 0) { red[0][wvv] = bce_p; red[1][wvv] = inter_p; red[2][wvv] = uni_p; }
    __syncthreads();
    if (threadIdx.x == 0) {
        atomicAdd(&acc[0], (double)(red[0][0] + red[0][1] + red[0][2] + red[0][3]));
        atomicAdd(&acc[1 + b], (double)(red[1][0] + red[1][1] + red[1][2] + red[1][3]));
        atomicAdd(&acc[65 + b], (double)(red[2][0] + red[2][1] + red[2][2] + red[2][3]));
    }
}

__global__ void finalize_atomic_kernel(const double* __restrict__ acc, float* __restrict__ out) {
    int b = threadIdx.x;
    double inter = acc[1 + b];
    double uni   = acc[65 + b];
    double wiou = 1.0 - (inter + 1.0) / (uni - inter + 1.0);
    #pragma unroll
    for (int off = 32; off; off >>= 1) wiou += __shfl_down(wiou, off, 64);
    if (b == 0) {
        double wbce = acc[0] / (double)NELEM;
        out[0] = (float)(wbce + wiou * (1.0 / 64.0));
    }
}

// ---------------------------------------------------------------------------
extern "C" void kernel_launch(void* const* d_in, const int* in_sizes, int n_in,
                              void* d_out, int out_size, void* d_ws, size_t ws_size,
                              hipStream_t stream) {
    const float* pred = (const float*)d_in[0];
    const float* mask = (const float*)d_in[1];
    float* out = (float*)d_out;

    const size_t part_bytes = (size_t)NBLK * 3 * sizeof(double);   // 24 KiB

    if (ws_size >= part_bytes) {
        double* partials = (double*)d_ws;
        fused_kernel<<<NBLK, 256, 0, stream>>>(pred, mask, partials);
        finalize_kernel<<<1, 256, 0, stream>>>(partials, out);
    } else {
        double* acc = (double*)d_ws;
        hipMemsetAsync(acc, 0, ACC_DOUBLES * sizeof(double), stream);
        rowpass_nows_kernel<<<BATCH * HH, 256, 0, stream>>>(pred, mask, acc);
        finalize_atomic_kernel<<<1, 64, 0, stream>>>(acc, out);
    }
}

// Round 16
// 49.478 us; speedup vs baseline: 1.4241x; 1.4241x over previous
//
#include <hip/hip_runtime.h>
#include <math.h>

// Problem constants
#define BATCH 64
#define HH 512
#define WW 512
#define PAD 15
#define NELEM ((size_t)BATCH * HH * WW)
#define INV_KK (1.0f / 961.0f)

#define TILE_H 32              // rows per block
#define NIT (TILE_H / 4)       // 8
#define BPI (HH / TILE_H)      // 16 blocks per image
#define NBLK (BATCH * BPI)     // 1024 blocks -> 4 blocks/CU
#define NXCD 8

typedef float f4 __attribute__((ext_vector_type(4)));

__device__ __forceinline__ float wave_reduce(float v) {
    #pragma unroll
    for (int off = 32; off; off >>= 1) v += __shfl_down(v, off, 64);
    return v;
}

// ---------------------------------------------------------------------------
// Wave64 inclusive add-scan via DPP (classic gfx9/CDNA sequence, rocPRIM
// path): row_shr:1/2/4/8 within 16-lane rows, then row_bcast15 (rows 1,3)
// and row_bcast31 (rows 2,3) to stitch. All VALU-latency (~4cy/step) vs
// __shfl_up's ds_bpermute chain (~35cy/step) — removes ~170cy of serial
// latency per row and all bpermute LDS traffic.
// bound_ctrl=true -> out-of-range lanes contribute 0; old=0 -> masked rows
// add 0. Both make the adds unconditional.
// ---------------------------------------------------------------------------
__device__ __forceinline__ float dpp_scan_incl(float x) {
    float v = x;
    int t;
    t = __builtin_amdgcn_update_dpp(0, __float_as_int(v), 0x111, 0xf, 0xf, true); // row_shr:1
    v += __int_as_float(t);
    t = __builtin_amdgcn_update_dpp(0, __float_as_int(v), 0x112, 0xf, 0xf, true); // row_shr:2
    v += __int_as_float(t);
    t = __builtin_amdgcn_update_dpp(0, __float_as_int(v), 0x114, 0xf, 0xf, true); // row_shr:4
    v += __int_as_float(t);
    t = __builtin_amdgcn_update_dpp(0, __float_as_int(v), 0x118, 0xf, 0xf, true); // row_shr:8
    v += __int_as_float(t);
    t = __builtin_amdgcn_update_dpp(0, __float_as_int(v), 0x142, 0xa, 0xf, true); // row_bcast15 -> rows 1,3
    v += __int_as_float(t);
    t = __builtin_amdgcn_update_dpp(0, __float_as_int(v), 0x143, 0xc, 0xf, true); // row_bcast31 -> rows 2,3
    v += __int_as_float(t);
    return v;
}

// ---------------------------------------------------------------------------
// R11 champion structure (51.5us), ONE isolated change: the 6-step
// __shfl_up (ds_bpermute) scan chain is replaced by the DPP scan above.
//  - prefetch: next iteration's add/sub mask rows in registers
//  - vrow double-buffered, 1 barrier per 4 rows
//  - wave-private P row, no scan->loss barrier
// ---------------------------------------------------------------------------
__global__ __launch_bounds__(256) void fused_kernel(const float* __restrict__ pred,
                                                    const float* __restrict__ mask,
                                                    double* __restrict__ partials) {
    __shared__ float vrow[2][4][WW];   // double-buffered vertical-sum rows
    __shared__ float P[4][WW];         // per-wave private prefix rows
    __shared__ float red[3][4];

    // XCD swizzle: xcd = f%8 (HW round-robin); each XCD owns 8 whole images.
    const int f    = blockIdx.x;
    const int xcd  = f & (NXCD - 1);
    const int slot = f >> 3;               // 0..127
    const int img  = xcd * 8 + (slot >> 4);
    const int tile = slot & (BPI - 1);

    const int tid  = threadIdx.x;
    const int lane = tid & 63;
    const int wv   = tid >> 6;
    const int h0   = tile * TILE_H;        // block's first output row (max 480)
    const int c0   = tid;                  // producer columns
    const int c1   = tid + 256;

    const float* mb = mask + (size_t)img * HH * WW;
    const float* pb = pred + (size_t)img * HH * WW;

    // --- init rolling vertical window for row h0: rows [max(0,h0-15), min(511,h0+15)]
    float r0 = 0.0f, r1 = 0.0f;
    {
        int lo = h0 - PAD; if (lo < 0) lo = 0;
        int hi = h0 + PAD; if (hi > HH - 1) hi = HH - 1;
        for (int y = lo; y <= hi; ++y) {
            r0 += mb[(size_t)y * WW + c0];
            r1 += mb[(size_t)y * WW + c1];
        }
    }

    // Prefetched add/sub rows for the upcoming iteration (rows h+16 / h-15
    // for h = hbase..hbase+3). 16 named registers.
    float pa0, pa1, pa2, pa3, ps0, ps1, ps2, ps3;   // column c0
    float qa0, qa1, qa2, qa3, qs0, qs1, qs2, qs3;   // column c1

    #define PREFETCH(ii)                                                       \
    {                                                                          \
        const int hb = h0 + 4 * (ii);                                          \
        const int a0r = hb + 16, a1r = hb + 17, a2r = hb + 18, a3r = hb + 19;  \
        const int s0r = hb - 15, s1r = hb - 14, s2r = hb - 13, s3r = hb - 12;  \
        pa0 = (a0r < HH) ? mb[(size_t)a0r * WW + c0] : 0.0f;                   \
        pa1 = (a1r < HH) ? mb[(size_t)a1r * WW + c0] : 0.0f;                   \
        pa2 = (a2r < HH) ? mb[(size_t)a2r * WW + c0] : 0.0f;                   \
        pa3 = (a3r < HH) ? mb[(size_t)a3r * WW + c0] : 0.0f;                   \
        ps0 = (s0r >= 0) ? mb[(size_t)s0r * WW + c0] : 0.0f;                   \
        ps1 = (s1r >= 0) ? mb[(size_t)s1r * WW + c0] : 0.0f;                   \
        ps2 = (s2r >= 0) ? mb[(size_t)s2r * WW + c0] : 0.0f;                   \
        ps3 = (s3r >= 0) ? mb[(size_t)s3r * WW + c0] : 0.0f;                   \
        qa0 = (a0r < HH) ? mb[(size_t)a0r * WW + c1] : 0.0f;                   \
        qa1 = (a1r < HH) ? mb[(size_t)a1r * WW + c1] : 0.0f;                   \
        qa2 = (a2r < HH) ? mb[(size_t)a2r * WW + c1] : 0.0f;                   \
        qa3 = (a3r < HH) ? mb[(size_t)a3r * WW + c1] : 0.0f;                   \
        qs0 = (s0r >= 0) ? mb[(size_t)s0r * WW + c1] : 0.0f;                   \
        qs1 = (s1r >= 0) ? mb[(size_t)s1r * WW + c1] : 0.0f;                   \
        qs2 = (s2r >= 0) ? mb[(size_t)s2r * WW + c1] : 0.0f;                   \
        qs3 = (s3r >= 0) ? mb[(size_t)s3r * WW + c1] : 0.0f;                   \
    }

    PREFETCH(0)

    float accb = 0.0f, acci = 0.0f, accu = 0.0f;

    #pragma unroll 1   // forbid outer unroll: protects the register budget
    for (int it = 0; it < NIT; ++it) {
        const int hbase = h0 + it * 4;
        float (*vb)[WW] = vrow[it & 1];

        // --- producer: pure LDS/VALU, consumes prefetched rows ---
        vb[0][c0] = r0; vb[0][c1] = r1; r0 += pa0 - ps0; r1 += qa0 - qs0;
        vb[1][c0] = r0; vb[1][c1] = r1; r0 += pa1 - ps1; r1 += qa1 - qs1;
        vb[2][c0] = r0; vb[2][c1] = r1; r0 += pa2 - ps2; r1 += qa2 - qs2;
        vb[3][c0] = r0; vb[3][c1] = r1; r0 += pa3 - ps3; r1 += qa3 - qs3;
        __syncthreads();   // vb visible to all waves (the only barrier)

        // --- issue next iteration's loads; latency hides under scan+loss ---
        if (it + 1 < NIT) PREFETCH(it + 1)

        // --- scan: wave wv prefix-scans vb[wv] into P[wv] (wave-private) ---
        const int h = hbase + wv;
        const size_t rbase = (size_t)h * WW;

        f4 va = *(const f4*)&vb[wv][8 * lane];
        f4 vbv = *(const f4*)&vb[wv][8 * lane + 4];
        float p0 = va.x;
        float p1 = p0 + va.y;
        float p2 = p1 + va.z;
        float p3 = p2 + va.w;
        float p4 = p3 + vbv.x;
        float p5 = p4 + vbv.y;
        float p6 = p5 + vbv.z;
        float p7 = p6 + vbv.w;
        const float lanesum = p7;
        const float incl = dpp_scan_incl(lanesum);   // DPP scan (the change)
        const float excl = incl - lanesum;
        f4 Pa, Pb;
        Pa.x = excl + p0; Pa.y = excl + p1; Pa.z = excl + p2; Pa.w = excl + p3;
        Pb.x = excl + p4; Pb.y = excl + p5; Pb.z = excl + p6; Pb.w = excl + p7;
        *(f4*)&P[wv][8 * lane]     = Pa;
        *(f4*)&P[wv][8 * lane + 4] = Pb;
        // no barrier: P[wv] is wave-private (same-wave DS ordering).

        // --- loss: lane owns w = lane + 64k of row hbase+wv ---
        #pragma unroll
        for (int k = 0; k < 8; ++k) {
            const int w = lane + 64 * k;
            int hiw = w + PAD; if (hiw > WW - 1) hiw = WW - 1;
            float s = P[wv][hiw];
            if (w >= PAD + 1) s -= P[wv][w - PAD - 1];

            const float m  = mb[rbase + w];
            const float pr = pb[rbase + w];

            const float weit = 1.0f + 5.0f * fabsf(s * INV_KK - m);
            const float e    = __expf(-fabsf(pr));
            const float bce  = fmaxf(pr, 0.0f) - pr * m + __logf(1.0f + e);
            const float inv  = __builtin_amdgcn_rcpf(1.0f + e);
            const float p    = (pr >= 0.0f) ? inv : e * inv;   // sigmoid(pr)

            accb += bce;
            acci += p * m * weit;
            accu += (p + m) * weit;
        }
        // no end barrier: vrow is double-buffered (R11 safety argument).
    }
    #undef PREFETCH

    // --- block reduction ---
    accb = wave_reduce(accb);
    acci = wave_reduce(acci);
    accu = wave_reduce(accu);
    if (lane == 0) { red[0][wv] = accb; red[1][wv] = acci; red[2][wv] = accu; }
    __syncthreads();
    if (tid == 0) {
        double bt = (double)red[0][0] + red[0][1] + red[0][2] + red[0][3];
        double it2 = (double)red[1][0] + red[1][1] + red[1][2] + red[1][3];
        double ut = (double)red[2][0] + red[2][1] + red[2][2] + red[2][3];
        const size_t pidx = (size_t)img * BPI + tile;   // un-swizzled index
        partials[pidx * 3 + 0] = bt;
        partials[pidx * 3 + 1] = it2;
        partials[pidx * 3 + 2] = ut;
    }
}

// ---------------------------------------------------------------------------
// Finalize from per-block partials (indexed img*BPI + tile), NBLK = 1024.
// ---------------------------------------------------------------------------
__global__ __launch_bounds__(256) void finalize_kernel(const double* __restrict__ partials,
                                                       float* __restrict__ out) {
    __shared__ double redbce[4];
    int tid = threadIdx.x, lane = tid & 63, wv = tid >> 6;

    double bsum = 0.0;
    for (int i = tid; i < NBLK; i += 256) bsum += partials[(size_t)i * 3 + 0];
    #pragma unroll
    for (int off = 32; off; off >>= 1) bsum += __shfl_down(bsum, off, 64);
    if (lane == 0) redbce[wv] = bsum;
    __syncthreads();

    double wiou_term = 0.0;
    if (tid < 64) {
        int bb = tid;
        double it = 0.0, ut = 0.0;
        for (int j = 0; j < BPI; ++j) {
            it += partials[(size_t)(bb * BPI + j) * 3 + 1];
            ut += partials[(size_t)(bb * BPI + j) * 3 + 2];
        }
        wiou_term = 1.0 - (it + 1.0) / (ut - it + 1.0);
    }
    if (wv == 0) {
        #pragma unroll
        for (int off = 32; off; off >>= 1) wiou_term += __shfl_down(wiou_term, off, 64);
    }
    if (tid == 0) {
        double wbce = (redbce[0] + redbce[1] + redbce[2] + redbce[3]) / (double)NELEM;
        out[0] = (float)(wbce + wiou_term * (1.0 / 64.0));
    }
}

// ---------------------------------------------------------------------------
// Fallback path (tiny ws): recompute vertical sums in-kernel + atomics.
// ---------------------------------------------------------------------------
#define ACC_DOUBLES 129
__global__ __launch_bounds__(256) void rowpass_nows_kernel(const float* __restrict__ pred,
                                                           const float* __restrict__ mask,
                                                           double* __restrict__ acc) {
    __shared__ float vrow1[WW];
    __shared__ float red[3][4];
    int b = blockIdx.x / HH;
    int h = blockIdx.x % HH;
    int lo = h - PAD; if (lo < 0) lo = 0;
    int hi = h + PAD; if (hi > HH - 1) hi = HH - 1;
    float s0 = 0.0f, s1 = 0.0f;
    const float* mb = mask + (size_t)b * HH * WW;
    for (int y = lo; y <= hi; ++y) {
        s0 += mb[(size_t)y * WW + threadIdx.x];
        s1 += mb[(size_t)y * WW + threadIdx.x + 256];
    }
    vrow1[threadIdx.x]       = s0;
    vrow1[threadIdx.x + 256] = s1;
    __syncthreads();

    size_t base = ((size_t)b * HH + h) * WW;
    float bce_p = 0.0f, inter_p = 0.0f, uni_p = 0.0f;
    for (int w = threadIdx.x; w < WW; w += 256) {
        int wlo = w - PAD; if (wlo < 0) wlo = 0;
        int whi = w + PAD; if (whi > WW - 1) whi = WW - 1;
        float s = 0.0f;
        for (int k = wlo; k <= whi; ++k) s += vrow1[k];
        float m  = mask[base + w];
        float pr = pred[base + w];
        float weit = 1.0f + 5.0f * fabsf(s * INV_KK - m);
        float e   = expf(-fabsf(pr));
        float bce = fmaxf(pr, 0.0f) - pr * m + log1pf(e);
        float inv = 1.0f / (1.0f + e);
        float p   = (pr >= 0.0f) ? inv : e * inv;
        bce_p += bce; inter_p += p * m * weit; uni_p += (p + m) * weit;
    }
    int lane = threadIdx.x & 63, wvv = threadIdx.x >> 6;
    bce_p = wave_reduce(bce_p); inter_p = wave_reduce(inter_p); uni_p = wave_reduce(uni_p);
    if (lane == 0) { red[0][wvv] = bce_p; red[1][wvv] = inter_p; red[2][wvv] = uni_p; }
    __syncthreads();
    if (threadIdx.x == 0) {
        atomicAdd(&acc[0], (double)(red[0][0] + red[0][1] + red[0][2] + red[0][3]));
        atomicAdd(&acc[1 + b], (double)(red[1][0] + red[1][1] + red[1][2] + red[1][3]));
        atomicAdd(&acc[65 + b], (double)(red[2][0] + red[2][1] + red[2][2] + red[2][3]));
    }
}

__global__ void finalize_atomic_kernel(const double* __restrict__ acc, float* __restrict__ out) {
    int b = threadIdx.x;
    double inter = acc[1 + b];
    double uni   = acc[65 + b];
    double wiou = 1.0 - (inter + 1.0) / (uni - inter + 1.0);
    #pragma unroll
    for (int off = 32; off; off >>= 1) wiou += __shfl_down(wiou, off, 64);
    if (b == 0) {
        double wbce = acc[0] / (double)NELEM;
        out[0] = (float)(wbce + wiou * (1.0 / 64.0));
    }
}

// ---------------------------------------------------------------------------
extern "C" void kernel_launch(void* const* d_in, const int* in_sizes, int n_in,
                              void* d_out, int out_size, void* d_ws, size_t ws_size,
                              hipStream_t stream) {
    const float* pred = (const float*)d_in[0];
    const float* mask = (const float*)d_in[1];
    float* out = (float*)d_out;

    const size_t part_bytes = (size_t)NBLK * 3 * sizeof(double);   // 24 KiB

    if (ws_size >= part_bytes) {
        double* partials = (double*)d_ws;
        fused_kernel<<<NBLK, 256, 0, stream>>>(pred, mask, partials);
        finalize_kernel<<<1, 256, 0, stream>>>(partials, out);
    } else {
        double* acc = (double*)d_ws;
        hipMemsetAsync(acc, 0, ACC_DOUBLES * sizeof(double), stream);
        rowpass_nows_kernel<<<BATCH * HH, 256, 0, stream>>>(pred, mask, acc);
        finalize_atomic_kernel<<<1, 64, 0, stream>>>(acc, out);
    }
}